// Round 5
// baseline (518.443 us; speedup 1.0000x reference)
//
#include <hip/hip_runtime.h>
#include <math.h>

#define NN 4096
#define TT 32
#define FF 7
#define HH 64
#define NHEAD 8
#define DOUT 8

__device__ __forceinline__ float sigm(float x){
  x = fminf(fmaxf(x, -30.f), 30.f);
  return 1.f / (1.f + __expf(-x));
}
__device__ __forceinline__ float tanh_fast(float x){
  x = fminf(fmaxf(x, -15.f), 15.f);
  float e = __expf(2.f*x);
  return (e - 1.f) / (e + 1.f);
}

// ---------------- K0: transpose small 64x64 weights to k-major ----------------
__global__ void k0_prep(const float* __restrict__ pw, const float* __restrict__ msw,
                        const float* __restrict__ mpw, const float* __restrict__ sw1,
                        float* __restrict__ wtproj, float* __restrict__ wtself,
                        float* __restrict__ wtpos, float* __restrict__ wtsem)
{
  int tid = threadIdx.x + blockIdx.x*blockDim.x;
  if (tid < 4096){
    int d = tid >> 6, k = tid & 63;
    wtproj[k*64+d] = pw[tid];
    wtself[k*64+d] = msw[tid];
    wtpos[k*64+d]  = mpw[tid];
    wtsem[k*64+d]  = sw1[tid];
  }
}

// ---------------- K1: GRU encoder ----------------
__global__ __launch_bounds__(256) void k1_gru(
    const float* __restrict__ x,      // [N][T][F]
    const float* __restrict__ Wih,    // [192][7]
    const float* __restrict__ Whh,    // [192][64]
    const float* __restrict__ bih, const float* __restrict__ bhh,
    float* __restrict__ hout)         // [N][64]
{
  __shared__ float s_whh[192*64];     // swizzled, 48KB
  __shared__ float s_h[16][64];       // 4KB
  __shared__ float s_x[4][448];       // per-wave x staging (4 nodes x 16 t x 7 f), 7KB

  int tid = threadIdx.x;
  int lane = tid & 63, wave = tid >> 6;

  for (int i = tid; i < 192*64; i += 256){
    int g = i >> 6, k = i & 63;
    s_whh[g*64 + (k ^ ((g & 7) << 2))] = Whh[i];
  }

  float wr_[7], wz_[7], wn_[7];
  #pragma unroll
  for (int f = 0; f < 7; ++f){
    wr_[f] = Wih[lane*7 + f];
    wz_[f] = Wih[(lane+64)*7 + f];
    wn_[f] = Wih[(lane+128)*7 + f];
  }
  float bir = bih[lane], biz = bih[lane+64], bin_ = bih[lane+128];
  float bhr = bhh[lane], bhz = bhh[lane+64], bhn = bhh[lane+128];

  int nb = blockIdx.x*16 + wave*4;    // first node of this wave
  #pragma unroll
  for (int n = 0; n < 4; ++n) s_h[wave*4+n][lane] = 0.f;
  float hreg[4] = {0.f, 0.f, 0.f, 0.f};
  __syncthreads();                    // only barrier: s_whh staging

  int sw = (lane & 7) << 2;           // word swizzle for this lane's rows
  const float* rowr = s_whh + lane*64;
  const float* rowz = s_whh + (lane+64)*64;
  const float* rown = s_whh + (lane+128)*64;

  for (int half = 0; half < 2; ++half){
    // stage x for this wave's 4 nodes, 16 timesteps (wave-private: no barrier)
    for (int i = lane; i < 448; i += 64){
      int n = i / 112, rem = i - n*112;
      s_x[wave][i] = x[(size_t)(nb + n)*224 + half*112 + rem];
    }
    for (int tt = 0; tt < 16; ++tt){
      float accr[4], accz[4], accn[4];
      #pragma unroll
      for (int n = 0; n < 4; ++n){ accr[n]=0.f; accz[n]=0.f; accn[n]=0.f; }
      #pragma unroll
      for (int k4 = 0; k4 < 16; ++k4){
        int off = (k4*4) ^ sw;
        float4 wr4 = *(const float4*)(rowr + off);
        float4 wz4 = *(const float4*)(rowz + off);
        float4 wn4 = *(const float4*)(rown + off);
        #pragma unroll
        for (int n = 0; n < 4; ++n){
          float4 h4 = *(const float4*)&s_h[wave*4+n][k4*4];   // broadcast read
          accr[n] += wr4.x*h4.x + wr4.y*h4.y + wr4.z*h4.z + wr4.w*h4.w;
          accz[n] += wz4.x*h4.x + wz4.y*h4.y + wz4.z*h4.z + wz4.w*h4.w;
          accn[n] += wn4.x*h4.x + wn4.y*h4.y + wn4.z*h4.z + wn4.w*h4.w;
        }
      }
      #pragma unroll
      for (int n = 0; n < 4; ++n){
        const float* xp = &s_x[wave][n*112 + tt*7];
        float gr = bir, gz = biz, gn = bin_;
        #pragma unroll
        for (int f = 0; f < 7; ++f){
          float xv = xp[f];
          gr += wr_[f]*xv; gz += wz_[f]*xv; gn += wn_[f]*xv;
        }
        float rr = sigm(gr + bhr + accr[n]);
        float zz = sigm(gz + bhz + accz[n]);
        float nn = tanh_fast(gn + rr*(bhn + accn[n]));
        float hn = (1.f - zz)*nn + zz*hreg[n];
        hreg[n] = hn;
        s_h[wave*4+n][lane] = hn;
      }
    }
  }
  #pragma unroll
  for (int n = 0; n < 4; ++n)
    hout[(size_t)(nb+n)*64 + lane] = hreg[n];
}

// ---------------- K2: sup (transposed) = h@gat_w, f1t/f2 head scalars, block f1 max ----------------
__global__ __launch_bounds__(256) void k2_sup(
    const float* __restrict__ h, const float* __restrict__ gat_w,
    const float* __restrict__ wu, const float* __restrict__ wv,
    float* __restrict__ supt,    // [64][N]  row = hh*8+o
    float* __restrict__ f1t,     // [8][N]
    float* __restrict__ f2,      // [N][8]
    float* __restrict__ bmax)
{
  int tid = threadIdx.x;
  int wave = tid >> 6, lane = tid & 63;
  int n = blockIdx.x*4 + wave;
  float hreg = h[n*64 + lane];
  float acc = 0.f;
  #pragma unroll
  for (int k = 0; k < 64; ++k){
    float hk = __shfl(hreg, k, 64);
    acc += hk * gat_w[k*64 + lane];
  }
  supt[(size_t)lane*NN + n] = acc;     // transposed write (j-major per head-out row)
  float p1 = acc * wu[lane];
  float p2 = acc * wv[lane];
  #pragma unroll
  for (int s = 1; s < 8; s <<= 1){
    p1 += __shfl_xor(p1, s, 64);
    p2 += __shfl_xor(p2, s, 64);
  }
  int hh = lane >> 3;
  __shared__ float s_m[4][8];
  if ((lane & 7) == 0){
    f1t[(size_t)hh*NN + n] = p1;
    f2[n*8 + hh] = p2;
    s_m[wave][hh] = p1;
  }
  __syncthreads();
  if (tid < 8){
    float mm = fmaxf(fmaxf(s_m[0][tid], s_m[1][tid]), fmaxf(s_m[2][tid], s_m[3][tid]));
    bmax[blockIdx.x*8 + tid] = mm;
  }
}

__global__ __launch_bounds__(256) void k2b_max(const float* __restrict__ bmax, float* __restrict__ maxf1)
{
  int tid = threadIdx.x;
  int hh = tid & 7, chunk = tid >> 3;   // 32 chunks of 32 blocks
  float m = -1e30f;
  for (int b = chunk*32; b < chunk*32+32; ++b) m = fmaxf(m, bmax[b*8 + hh]);
  __shared__ float sm[256];
  sm[tid] = m;
  __syncthreads();
  if (tid < 8){
    float mm = -1e30f;
    for (int c = 0; c < 32; ++c) mm = fmaxf(mm, sm[c*8 + tid]);
    maxf1[tid] = mm;
  }
}

// ---------------- K2c: pack adjacency rows into 64-bit masks ----------------
__global__ __launch_bounds__(256) void k2c_pack(const int* __restrict__ adj,
                                               unsigned long long* __restrict__ adjm)
{
  int lane = threadIdx.x & 63, wave = threadIdx.x >> 6;
  int row = blockIdx.x*4 + wave;
  const int* ap = adj + (size_t)row*NN;
  #pragma unroll 8
  for (int s = 0; s < 64; ++s){
    unsigned long long m = __ballot(ap[s*64 + lane] != 0);
    if (lane == 0) adjm[(size_t)row*64 + s] = m;
  }
}

// ---------------- K3: masked-softmax GAT, one wave per (row, head) ----------------
// 8192 blocks x 256 threads (4 waves). No LDS, no barriers, no merge tree.
// Lane covers 2 j per batch via float2; all loads coalesced; mask is 2-line broadcast.
__global__ __launch_bounds__(256) void k3_gat(
    const unsigned long long* __restrict__ adjm,   // [N][64]
    const float* __restrict__ supt,                // [64][N]
    const float* __restrict__ f1t,                 // [8][N]
    const float* __restrict__ f2,                  // [N][8]
    const float* __restrict__ maxf1, float* __restrict__ posg)
{
  int tid = threadIdx.x;
  int lane = tid & 63, wave = tid >> 6;
  int gid = blockIdx.x*4 + wave;        // 0..32767
  int i = gid >> 3, h = gid & 7;

  float f2v = f2[(size_t)i*8 + h];
  float lg = maxf1[h] + f2v;
  lg = fmaxf(lg, 0.2f*lg);
  float M = fmaxf(lg, 0.f);            // upper bound on reference rowmax

  const float2* f1p = (const float2*)(f1t + (size_t)h*NN);
  const float2* sp0 = (const float2*)(supt + (size_t)(h*8+0)*NN);
  const float2* sp1 = (const float2*)(supt + (size_t)(h*8+1)*NN);
  const float2* sp2 = (const float2*)(supt + (size_t)(h*8+2)*NN);
  const float2* sp3 = (const float2*)(supt + (size_t)(h*8+3)*NN);
  const float2* sp4 = (const float2*)(supt + (size_t)(h*8+4)*NN);
  const float2* sp5 = (const float2*)(supt + (size_t)(h*8+5)*NN);
  const float2* sp6 = (const float2*)(supt + (size_t)(h*8+6)*NN);
  const float2* sp7 = (const float2*)(supt + (size_t)(h*8+7)*NN);
  const unsigned long long* mrow = adjm + (size_t)i*64;

  int half = lane >> 5;
  int b0 = (lane*2) & 63;
  float sum = 0.f;
  float pos[8] = {0.f,0.f,0.f,0.f,0.f,0.f,0.f,0.f};

  for (int b = 0; b < 32; ++b){
    unsigned long long mw = mrow[b*2 + half];   // broadcast (2 lines per wave)
    int idx = b*64 + lane;
    float2 f1v = f1p[idx];
    float2 s0 = sp0[idx], s1 = sp1[idx], s2 = sp2[idx], s3 = sp3[idx];
    float2 s4 = sp4[idx], s5 = sp5[idx], s6 = sp6[idx], s7 = sp7[idx];
    float l0 = f1v.x + f2v, l1 = f1v.y + f2v;
    l0 = fmaxf(l0, 0.2f*l0);
    l1 = fmaxf(l1, 0.2f*l1);
    float p0 = __expf(l0 - M);
    float p1 = __expf(l1 - M);
    p0 = ((mw >> b0) & 1ull) ? p0 : 0.f;
    p1 = ((mw >> (b0+1)) & 1ull) ? p1 : 0.f;
    sum += p0 + p1;
    pos[0] += p0*s0.x + p1*s0.y;
    pos[1] += p0*s1.x + p1*s1.y;
    pos[2] += p0*s2.x + p1*s2.y;
    pos[3] += p0*s3.x + p1*s3.y;
    pos[4] += p0*s4.x + p1*s4.y;
    pos[5] += p0*s5.x + p1*s5.y;
    pos[6] += p0*s6.x + p1*s6.y;
    pos[7] += p0*s7.x + p1*s7.y;
  }

  // 64-lane butterfly reduce of 9 values
  #pragma unroll
  for (int s = 1; s < 64; s <<= 1){
    sum += __shfl_xor(sum, s, 64);
    #pragma unroll
    for (int o = 0; o < 8; ++o) pos[o] += __shfl_xor(pos[o], s, 64);
  }
  if (lane == 0){
    float inv = 1.f / fmaxf(sum, 1e-10f);
    float* dst = &posg[(size_t)i*64 + h*8];
    #pragma unroll
    for (int o = 0; o < 8; ++o) dst[o] = pos[o]*inv;
  }
}

// ---------------- K4: residual proj + the two MLP channels + PairNorm partials ----------------
__global__ __launch_bounds__(256) void k4_mix(
    const float* __restrict__ h, const float* __restrict__ posg,
    const float* __restrict__ gat_bias, const float* __restrict__ proj_b,
    const float* __restrict__ wtproj, const float* __restrict__ wtself,
    const float* __restrict__ wtpos,
    const float* __restrict__ mlp_self_b, const float* __restrict__ mlp_pos_b,
    float* __restrict__ s0, float* __restrict__ s1, float* __restrict__ part)
{
  int tid = threadIdx.x;
  int wave = tid >> 6, lane = tid & 63;
  int n = blockIdx.x*4 + wave;
  float hreg = h[n*64 + lane];
  float pr = proj_b[lane];
  float se = mlp_self_b[lane];
  #pragma unroll
  for (int k = 0; k < 64; ++k){
    float hk = __shfl(hreg, k, 64);
    pr += hk * wtproj[k*64 + lane];
    se += hk * wtself[k*64 + lane];
  }
  float posf = posg[n*64 + lane] + gat_bias[lane] + pr;
  float s1v = mlp_pos_b[lane];
  #pragma unroll
  for (int k = 0; k < 64; ++k){
    float pk = __shfl(posf, k, 64);
    s1v += pk * wtpos[k*64 + lane];
  }
  s0[n*64+lane] = se;
  s1[n*64+lane] = s1v;

  __shared__ float sb0[4][64];
  __shared__ float sb1[4][64];
  __shared__ float sq[4];
  sb0[wave][lane] = se;
  sb1[wave][lane] = s1v;
  float q = se*se + s1v*s1v;
  #pragma unroll
  for (int s = 1; s < 64; s <<= 1) q += __shfl_xor(q, s, 64);
  if (lane == 0) sq[wave] = q;
  __syncthreads();
  if (tid < 64){
    part[blockIdx.x*130 + tid] = sb0[0][tid]+sb0[1][tid]+sb0[2][tid]+sb0[3][tid];
  } else if (tid < 128){
    int d = tid - 64;
    part[blockIdx.x*130 + 64 + d] = sb1[0][d]+sb1[1][d]+sb1[2][d]+sb1[3][d];
  } else if (tid == 128){
    part[blockIdx.x*130 + 128] = sq[0]+sq[1]+sq[2]+sq[3];
  }
}

// ---------------- K5: PairNorm stats (1024-thread two-stage reduce) ----------------
__global__ __launch_bounds__(1024) void k5_stats(const float* __restrict__ part, float* __restrict__ stats)
{
  int tid = threadIdx.x;
  __shared__ float s_mu[8][128];
  __shared__ float s_sq[8];
  int c = tid & 127, ch = tid >> 7;
  float a = 0.f;
  for (int b = ch*128; b < ch*128+128; ++b) a += part[b*130 + c];
  s_mu[ch][c] = a;
  if (tid < 8){
    float q = 0.f;
    for (int b = tid*128; b < tid*128+128; ++b) q += part[b*130 + 128];
    s_sq[tid] = q;
  }
  __syncthreads();
  if (tid < 128){
    float m = 0.f;
    #pragma unroll
    for (int j = 0; j < 8; ++j) m += s_mu[j][tid];
    s_mu[0][tid] = m;
    stats[tid] = m / 4096.f;
  }
  __syncthreads();
  if (tid == 0){
    float sq = 0.f;
    #pragma unroll
    for (int j = 0; j < 8; ++j) sq += s_sq[j];
    float mu2 = 0.f;
    for (int i = 0; i < 128; ++i){ float m = s_mu[0][i] / 4096.f; mu2 += m*m; }
    float msq = sq/(4096.f*64.f) - mu2/64.f;
    stats[128] = 1.f / sqrtf(1e-6f + msq);
  }
}

// ---------------- K6: semantic attention + predictor ----------------
__global__ __launch_bounds__(256) void k6_sem(
    const float* __restrict__ s0, const float* __restrict__ s1,
    const float* __restrict__ stats, const float* __restrict__ wtsem,
    const float* __restrict__ sem_b1, const float* __restrict__ sem_w2,
    const float* __restrict__ pred_w, const float* __restrict__ pred_b,
    float* __restrict__ out)
{
  int tid = threadIdx.x;
  int wave = tid >> 6, lane = tid & 63;
  int n = blockIdx.x*4 + wave;
  float rinv = stats[128];
  float a0 = (s0[n*64+lane] - stats[lane]) * rinv;
  float a1 = (s1[n*64+lane] - stats[64+lane]) * rinv;
  float t0 = sem_b1[lane], t1 = t0;
  #pragma unroll
  for (int k = 0; k < 64; ++k){
    float w = wtsem[k*64 + lane];
    t0 += __shfl(a0, k, 64) * w;
    t1 += __shfl(a1, k, 64) * w;
  }
  t0 = tanh_fast(t0); t1 = tanh_fast(t1);
  float w2 = sem_w2[lane];
  float w0 = t0*w2, w1 = t1*w2;
  #pragma unroll
  for (int s = 1; s < 64; s <<= 1){
    w0 += __shfl_xor(w0, s, 64);
    w1 += __shfl_xor(w1, s, 64);
  }
  float mx = fmaxf(w0, w1);
  float e0 = __expf(w0 - mx), e1 = __expf(w1 - mx);
  float denom = e0 + e1 + 1e-10f;
  float b0 = e0/denom, b1 = e1/denom;
  float emb = b0*a0 + b1*a1;
  float pl = emb * pred_w[lane];
  #pragma unroll
  for (int s = 1; s < 64; s <<= 1) pl += __shfl_xor(pl, s, 64);
  if (lane == 0) out[n] = sigm(pl + pred_b[0]);
}

extern "C" void kernel_launch(void* const* d_in, const int* in_sizes, int n_in,
                              void* d_out, int out_size, void* d_ws, size_t ws_size,
                              hipStream_t stream)
{
  (void)in_sizes; (void)n_in; (void)out_size; (void)ws_size;
  const float* x         = (const float*)d_in[0];
  const int*   adj       = (const int*)d_in[1];
  const float* W_ih      = (const float*)d_in[2];
  const float* W_hh      = (const float*)d_in[3];
  const float* b_ih      = (const float*)d_in[4];
  const float* b_hh      = (const float*)d_in[5];
  const float* gat_w     = (const float*)d_in[6];
  const float* gat_wu    = (const float*)d_in[7];
  const float* gat_wv    = (const float*)d_in[8];
  const float* gat_bias  = (const float*)d_in[9];
  const float* proj_w    = (const float*)d_in[10];
  const float* proj_b    = (const float*)d_in[11];
  const float* mlp_self_w= (const float*)d_in[12];
  const float* mlp_self_b= (const float*)d_in[13];
  const float* mlp_pos_w = (const float*)d_in[14];
  const float* mlp_pos_b = (const float*)d_in[15];
  const float* sem_w1    = (const float*)d_in[16];
  const float* sem_b1    = (const float*)d_in[17];
  const float* sem_w2    = (const float*)d_in[18];
  const float* pred_w    = (const float*)d_in[19];
  const float* pred_b    = (const float*)d_in[20];
  float* out = (float*)d_out;
  float* ws  = (float*)d_ws;

  float* h     = ws + 0;         // 262144
  float* supt  = ws + 262144;    // 262144  [64][4096]
  float* f1t   = ws + 524288;    // 32768   [8][4096]
  float* f2    = ws + 557056;    // 32768   [4096][8]
  float* posg  = ws + 589824;    // 262144
  float* s0    = ws + 851968;    // 262144
  float* s1    = ws + 1114112;   // 262144
  // adjm overlays s0+s1 (2MB): written by k2c, consumed by k3, dead before k4 writes s0/s1
  unsigned long long* adjm = (unsigned long long*)(ws + 851968);
  float* part  = ws + 1376256;   // 1024*130
  float* bmax  = ws + 1509376;   // 1024*8
  float* maxf1 = ws + 1517568;   // 8
  float* stats = ws + 1517576;   // 129
  float* wtproj= ws + 1517712;   // 4096
  float* wtself= wtproj + 4096;
  float* wtpos = wtself + 4096;
  float* wtsem = wtpos  + 4096;

  k0_prep<<<16, 256, 0, stream>>>(proj_w, mlp_self_w, mlp_pos_w, sem_w1,
                                  wtproj, wtself, wtpos, wtsem);
  k1_gru<<<256, 256, 0, stream>>>(x, W_ih, W_hh, b_ih, b_hh, h);
  k2_sup<<<1024, 256, 0, stream>>>(h, gat_w, gat_wu, gat_wv, supt, f1t, f2, bmax);
  k2b_max<<<1, 256, 0, stream>>>(bmax, maxf1);
  k2c_pack<<<1024, 256, 0, stream>>>(adj, adjm);
  k3_gat<<<8192, 256, 0, stream>>>(adjm, supt, f1t, f2, maxf1, posg);
  k4_mix<<<1024, 256, 0, stream>>>(h, posg, gat_bias, proj_b, wtproj, wtself, wtpos,
                                   mlp_self_b, mlp_pos_b, s0, s1, part);
  k5_stats<<<1, 1024, 0, stream>>>(part, stats);
  k6_sem<<<1024, 256, 0, stream>>>(s0, s1, stats, wtsem, sem_b1, sem_w2, pred_w, pred_b, out);
}

// Round 6
// 349.956 us; speedup vs baseline: 1.4815x; 1.4815x over previous
//
#include <hip/hip_runtime.h>
#include <math.h>

#define NN 4096
#define TT 32
#define FF 7
#define HH 64
#define NHEAD 8
#define DOUT 8

__device__ __forceinline__ float sigm(float x){
  x = fminf(fmaxf(x, -30.f), 30.f);
  return 1.f / (1.f + __expf(-x));
}
__device__ __forceinline__ float tanh_fast(float x){
  x = fminf(fmaxf(x, -15.f), 15.f);
  float e = __expf(2.f*x);
  return (e - 1.f) / (e + 1.f);
}

// ---------------- K0: transpose small 64x64 weights to k-major ----------------
__global__ void k0_prep(const float* __restrict__ pw, const float* __restrict__ msw,
                        const float* __restrict__ mpw, const float* __restrict__ sw1,
                        float* __restrict__ wtproj, float* __restrict__ wtself,
                        float* __restrict__ wtpos, float* __restrict__ wtsem)
{
  int tid = threadIdx.x + blockIdx.x*blockDim.x;
  if (tid < 4096){
    int d = tid >> 6, k = tid & 63;
    wtproj[k*64+d] = pw[tid];
    wtself[k*64+d] = msw[tid];
    wtpos[k*64+d]  = mpw[tid];
    wtsem[k*64+d]  = sw1[tid];
  }
}

// ---------------- K1: GRU encoder ----------------
__global__ __launch_bounds__(256) void k1_gru(
    const float* __restrict__ x,      // [N][T][F]
    const float* __restrict__ Wih,    // [192][7]
    const float* __restrict__ Whh,    // [192][64]
    const float* __restrict__ bih, const float* __restrict__ bhh,
    float* __restrict__ hout)         // [N][64]
{
  __shared__ float s_whh[192*64];     // swizzled, 48KB
  __shared__ float s_h[16][64];       // 4KB
  __shared__ float s_x[4][448];       // per-wave x staging (4 nodes x 16 t x 7 f), 7KB

  int tid = threadIdx.x;
  int lane = tid & 63, wave = tid >> 6;

  for (int i = tid; i < 192*64; i += 256){
    int g = i >> 6, k = i & 63;
    s_whh[g*64 + (k ^ ((g & 7) << 2))] = Whh[i];
  }

  float wr_[7], wz_[7], wn_[7];
  #pragma unroll
  for (int f = 0; f < 7; ++f){
    wr_[f] = Wih[lane*7 + f];
    wz_[f] = Wih[(lane+64)*7 + f];
    wn_[f] = Wih[(lane+128)*7 + f];
  }
  float bir = bih[lane], biz = bih[lane+64], bin_ = bih[lane+128];
  float bhr = bhh[lane], bhz = bhh[lane+64], bhn = bhh[lane+128];

  int nb = blockIdx.x*16 + wave*4;    // first node of this wave
  #pragma unroll
  for (int n = 0; n < 4; ++n) s_h[wave*4+n][lane] = 0.f;
  float hreg[4] = {0.f, 0.f, 0.f, 0.f};
  __syncthreads();                    // only barrier: s_whh staging

  int sw = (lane & 7) << 2;           // word swizzle for this lane's rows
  const float* rowr = s_whh + lane*64;
  const float* rowz = s_whh + (lane+64)*64;
  const float* rown = s_whh + (lane+128)*64;

  for (int half = 0; half < 2; ++half){
    // stage x for this wave's 4 nodes, 16 timesteps (wave-private: no barrier)
    for (int i = lane; i < 448; i += 64){
      int n = i / 112, rem = i - n*112;
      s_x[wave][i] = x[(size_t)(nb + n)*224 + half*112 + rem];
    }
    for (int tt = 0; tt < 16; ++tt){
      float accr[4], accz[4], accn[4];
      #pragma unroll
      for (int n = 0; n < 4; ++n){ accr[n]=0.f; accz[n]=0.f; accn[n]=0.f; }
      #pragma unroll
      for (int k4 = 0; k4 < 16; ++k4){
        int off = (k4*4) ^ sw;
        float4 wr4 = *(const float4*)(rowr + off);
        float4 wz4 = *(const float4*)(rowz + off);
        float4 wn4 = *(const float4*)(rown + off);
        #pragma unroll
        for (int n = 0; n < 4; ++n){
          float4 h4 = *(const float4*)&s_h[wave*4+n][k4*4];   // broadcast read
          accr[n] += wr4.x*h4.x + wr4.y*h4.y + wr4.z*h4.z + wr4.w*h4.w;
          accz[n] += wz4.x*h4.x + wz4.y*h4.y + wz4.z*h4.z + wz4.w*h4.w;
          accn[n] += wn4.x*h4.x + wn4.y*h4.y + wn4.z*h4.z + wn4.w*h4.w;
        }
      }
      #pragma unroll
      for (int n = 0; n < 4; ++n){
        const float* xp = &s_x[wave][n*112 + tt*7];
        float gr = bir, gz = biz, gn = bin_;
        #pragma unroll
        for (int f = 0; f < 7; ++f){
          float xv = xp[f];
          gr += wr_[f]*xv; gz += wz_[f]*xv; gn += wn_[f]*xv;
        }
        float rr = sigm(gr + bhr + accr[n]);
        float zz = sigm(gz + bhz + accz[n]);
        float nn = tanh_fast(gn + rr*(bhn + accn[n]));
        float hn = (1.f - zz)*nn + zz*hreg[n];
        hreg[n] = hn;
        s_h[wave*4+n][lane] = hn;
      }
    }
  }
  #pragma unroll
  for (int n = 0; n < 4; ++n)
    hout[(size_t)(nb+n)*64 + lane] = hreg[n];
}

// ---------------- K2: sup (transposed) = h@gat_w, f1t/f2 head scalars, block f1 max ----------------
__global__ __launch_bounds__(256) void k2_sup(
    const float* __restrict__ h, const float* __restrict__ gat_w,
    const float* __restrict__ wu, const float* __restrict__ wv,
    float* __restrict__ supt,    // [64][N]  row = hh*8+o
    float* __restrict__ f1t,     // [8][N]
    float* __restrict__ f2,      // [N][8]
    float* __restrict__ bmax)
{
  int tid = threadIdx.x;
  int wave = tid >> 6, lane = tid & 63;
  int n = blockIdx.x*4 + wave;
  float hreg = h[n*64 + lane];
  float acc = 0.f;
  #pragma unroll
  for (int k = 0; k < 64; ++k){
    float hk = __shfl(hreg, k, 64);
    acc += hk * gat_w[k*64 + lane];
  }
  supt[(size_t)lane*NN + n] = acc;     // transposed write (j-major per head-out row)
  float p1 = acc * wu[lane];
  float p2 = acc * wv[lane];
  #pragma unroll
  for (int s = 1; s < 8; s <<= 1){
    p1 += __shfl_xor(p1, s, 64);
    p2 += __shfl_xor(p2, s, 64);
  }
  int hh = lane >> 3;
  __shared__ float s_m[4][8];
  if ((lane & 7) == 0){
    f1t[(size_t)hh*NN + n] = p1;
    f2[n*8 + hh] = p2;
    s_m[wave][hh] = p1;
  }
  __syncthreads();
  if (tid < 8){
    float mm = fmaxf(fmaxf(s_m[0][tid], s_m[1][tid]), fmaxf(s_m[2][tid], s_m[3][tid]));
    bmax[blockIdx.x*8 + tid] = mm;
  }
}

__global__ __launch_bounds__(256) void k2b_max(const float* __restrict__ bmax, float* __restrict__ maxf1)
{
  int tid = threadIdx.x;
  int hh = tid & 7, chunk = tid >> 3;   // 32 chunks of 32 blocks
  float m = -1e30f;
  for (int b = chunk*32; b < chunk*32+32; ++b) m = fmaxf(m, bmax[b*8 + hh]);
  __shared__ float sm[256];
  sm[tid] = m;
  __syncthreads();
  if (tid < 8){
    float mm = -1e30f;
    for (int c = 0; c < 32; ++c) mm = fmaxf(mm, sm[c*8 + tid]);
    maxf1[tid] = mm;
  }
}

// ---------------- K2c: pack adjacency rows into 64-bit masks ----------------
__global__ __launch_bounds__(256) void k2c_pack(const int* __restrict__ adj,
                                               unsigned long long* __restrict__ adjm)
{
  int lane = threadIdx.x & 63, wave = threadIdx.x >> 6;
  int row = blockIdx.x*4 + wave;
  const int* ap = adj + (size_t)row*NN;
  #pragma unroll 8
  for (int s = 0; s < 64; ++s){
    unsigned long long m = __ballot(ap[s*64 + lane] != 0);
    if (lane == 0) adjm[(size_t)row*64 + s] = m;
  }
}

// ---------------- K3: masked-softmax GAT, one wave per (8 rows, 1 head) ----------------
// 1024 blocks x 256 threads (4 waves = 4 (rowblock,head) units). The 9 streamed
// float2 loads per 128-j batch are amortized over 8 rows of VALU work: L2 traffic
// drops 8x vs one-row-per-wave; inner loop is FMA-dominated.
__global__ __launch_bounds__(256) void k3_gat(
    const unsigned long long* __restrict__ adjm,   // [N][64]
    const float* __restrict__ supt,                // [64][N]
    const float* __restrict__ f1t,                 // [8][N]
    const float* __restrict__ f2,                  // [N][8]
    const float* __restrict__ maxf1, float* __restrict__ posg)
{
  int tid = threadIdx.x;
  int lane = tid & 63, wave = tid >> 6;
  int gid = blockIdx.x*4 + wave;        // 0..4095
  int ib = gid >> 3, h = gid & 7;
  int i0 = ib*8;

  float mf = maxf1[h];
  float f2v[8], M[8];
  #pragma unroll
  for (int r = 0; r < 8; ++r){
    f2v[r] = f2[(size_t)(i0+r)*8 + h];
    float lg = mf + f2v[r];
    lg = fmaxf(lg, 0.2f*lg);
    M[r] = fmaxf(lg, 0.f);              // upper bound on reference rowmax
  }

  const float2* f1p = (const float2*)(f1t + (size_t)h*NN);
  const float2* sp0 = (const float2*)(supt + (size_t)(h*8+0)*NN);
  const float2* sp1 = (const float2*)(supt + (size_t)(h*8+1)*NN);
  const float2* sp2 = (const float2*)(supt + (size_t)(h*8+2)*NN);
  const float2* sp3 = (const float2*)(supt + (size_t)(h*8+3)*NN);
  const float2* sp4 = (const float2*)(supt + (size_t)(h*8+4)*NN);
  const float2* sp5 = (const float2*)(supt + (size_t)(h*8+5)*NN);
  const float2* sp6 = (const float2*)(supt + (size_t)(h*8+6)*NN);
  const float2* sp7 = (const float2*)(supt + (size_t)(h*8+7)*NN);
  const unsigned long long* mbase = adjm + (size_t)i0*64;

  int sh0 = (lane*2) & 63;              // bit position of this lane's first j
  int woff = (lane >> 5);               // which of the 2 words this iter

  float sum[8] = {0.f,0.f,0.f,0.f,0.f,0.f,0.f,0.f};
  float pos[8][8];
  #pragma unroll
  for (int r = 0; r < 8; ++r)
    #pragma unroll
    for (int o = 0; o < 8; ++o) pos[r][o] = 0.f;

  for (int b = 0; b < 32; ++b){         // 128 j per iter (2 j per lane)
    int idx = b*64 + lane;
    float2 f1v = f1p[idx];
    float2 s0 = sp0[idx], s1 = sp1[idx], s2 = sp2[idx], s3 = sp3[idx];
    float2 s4 = sp4[idx], s5 = sp5[idx], s6 = sp6[idx], s7 = sp7[idx];
    int w = b*2 + woff;
    unsigned long long mw[8];
    #pragma unroll
    for (int r = 0; r < 8; ++r) mw[r] = mbase[r*64 + w];

    #pragma unroll
    for (int r = 0; r < 8; ++r){
      float l0 = f1v.x + f2v[r];
      float l1 = f1v.y + f2v[r];
      l0 = fmaxf(l0, 0.2f*l0);
      l1 = fmaxf(l1, 0.2f*l1);
      float p0 = __expf(l0 - M[r]);
      float p1 = __expf(l1 - M[r]);
      p0 = ((mw[r] >> sh0) & 1ull) ? p0 : 0.f;
      p1 = ((mw[r] >> (sh0+1)) & 1ull) ? p1 : 0.f;
      sum[r] += p0 + p1;
      pos[r][0] += p0*s0.x + p1*s0.y;
      pos[r][1] += p0*s1.x + p1*s1.y;
      pos[r][2] += p0*s2.x + p1*s2.y;
      pos[r][3] += p0*s3.x + p1*s3.y;
      pos[r][4] += p0*s4.x + p1*s4.y;
      pos[r][5] += p0*s5.x + p1*s5.y;
      pos[r][6] += p0*s6.x + p1*s6.y;
      pos[r][7] += p0*s7.x + p1*s7.y;
    }
  }

  // butterfly reduce all 72 accumulators across the wave
  #pragma unroll
  for (int s = 1; s < 64; s <<= 1){
    #pragma unroll
    for (int r = 0; r < 8; ++r){
      sum[r] += __shfl_xor(sum[r], s, 64);
      #pragma unroll
      for (int o = 0; o < 8; ++o) pos[r][o] += __shfl_xor(pos[r][o], s, 64);
    }
  }

  // lane (r*8+o) stores pos[r][o]/sum[r]  (static-index selection, rule #20)
  int lr = lane >> 3, lo = lane & 7;
  float sv = sum[0];
  #pragma unroll
  for (int r = 1; r < 8; ++r) sv = (lr == r) ? sum[r] : sv;
  float val = pos[0][0];
  #pragma unroll
  for (int r = 0; r < 8; ++r)
    #pragma unroll
    for (int o = 0; o < 8; ++o)
      if (r + o) val = (lane == r*8+o) ? pos[r][o] : val;
  float inv = 1.f / fmaxf(sv, 1e-10f);
  posg[(size_t)(i0 + lr)*64 + h*8 + lo] = val * inv;
}

// ---------------- K4: residual proj + the two MLP channels + PairNorm partials ----------------
__global__ __launch_bounds__(256) void k4_mix(
    const float* __restrict__ h, const float* __restrict__ posg,
    const float* __restrict__ gat_bias, const float* __restrict__ proj_b,
    const float* __restrict__ wtproj, const float* __restrict__ wtself,
    const float* __restrict__ wtpos,
    const float* __restrict__ mlp_self_b, const float* __restrict__ mlp_pos_b,
    float* __restrict__ s0, float* __restrict__ s1, float* __restrict__ part)
{
  int tid = threadIdx.x;
  int wave = tid >> 6, lane = tid & 63;
  int n = blockIdx.x*4 + wave;
  float hreg = h[n*64 + lane];
  float pr = proj_b[lane];
  float se = mlp_self_b[lane];
  #pragma unroll
  for (int k = 0; k < 64; ++k){
    float hk = __shfl(hreg, k, 64);
    pr += hk * wtproj[k*64 + lane];
    se += hk * wtself[k*64 + lane];
  }
  float posf = posg[n*64 + lane] + gat_bias[lane] + pr;
  float s1v = mlp_pos_b[lane];
  #pragma unroll
  for (int k = 0; k < 64; ++k){
    float pk = __shfl(posf, k, 64);
    s1v += pk * wtpos[k*64 + lane];
  }
  s0[n*64+lane] = se;
  s1[n*64+lane] = s1v;

  __shared__ float sb0[4][64];
  __shared__ float sb1[4][64];
  __shared__ float sq[4];
  sb0[wave][lane] = se;
  sb1[wave][lane] = s1v;
  float q = se*se + s1v*s1v;
  #pragma unroll
  for (int s = 1; s < 64; s <<= 1) q += __shfl_xor(q, s, 64);
  if (lane == 0) sq[wave] = q;
  __syncthreads();
  if (tid < 64){
    part[blockIdx.x*130 + tid] = sb0[0][tid]+sb0[1][tid]+sb0[2][tid]+sb0[3][tid];
  } else if (tid < 128){
    int d = tid - 64;
    part[blockIdx.x*130 + 64 + d] = sb1[0][d]+sb1[1][d]+sb1[2][d]+sb1[3][d];
  } else if (tid == 128){
    part[blockIdx.x*130 + 128] = sq[0]+sq[1]+sq[2]+sq[3];
  }
}

// ---------------- K5: PairNorm stats (1024-thread two-stage reduce) ----------------
__global__ __launch_bounds__(1024) void k5_stats(const float* __restrict__ part, float* __restrict__ stats)
{
  int tid = threadIdx.x;
  __shared__ float s_mu[8][128];
  __shared__ float s_sq[8];
  int c = tid & 127, ch = tid >> 7;
  float a = 0.f;
  for (int b = ch*128; b < ch*128+128; ++b) a += part[b*130 + c];
  s_mu[ch][c] = a;
  if (tid < 8){
    float q = 0.f;
    for (int b = tid*128; b < tid*128+128; ++b) q += part[b*130 + 128];
    s_sq[tid] = q;
  }
  __syncthreads();
  if (tid < 128){
    float m = 0.f;
    #pragma unroll
    for (int j = 0; j < 8; ++j) m += s_mu[j][tid];
    s_mu[0][tid] = m;
    stats[tid] = m / 4096.f;
  }
  __syncthreads();
  if (tid == 0){
    float sq = 0.f;
    #pragma unroll
    for (int j = 0; j < 8; ++j) sq += s_sq[j];
    float mu2 = 0.f;
    for (int i = 0; i < 128; ++i){ float m = s_mu[0][i] / 4096.f; mu2 += m*m; }
    float msq = sq/(4096.f*64.f) - mu2/64.f;
    stats[128] = 1.f / sqrtf(1e-6f + msq);
  }
}

// ---------------- K6: semantic attention + predictor ----------------
__global__ __launch_bounds__(256) void k6_sem(
    const float* __restrict__ s0, const float* __restrict__ s1,
    const float* __restrict__ stats, const float* __restrict__ wtsem,
    const float* __restrict__ sem_b1, const float* __restrict__ sem_w2,
    const float* __restrict__ pred_w, const float* __restrict__ pred_b,
    float* __restrict__ out)
{
  int tid = threadIdx.x;
  int wave = tid >> 6, lane = tid & 63;
  int n = blockIdx.x*4 + wave;
  float rinv = stats[128];
  float a0 = (s0[n*64+lane] - stats[lane]) * rinv;
  float a1 = (s1[n*64+lane] - stats[64+lane]) * rinv;
  float t0 = sem_b1[lane], t1 = t0;
  #pragma unroll
  for (int k = 0; k < 64; ++k){
    float w = wtsem[k*64 + lane];
    t0 += __shfl(a0, k, 64) * w;
    t1 += __shfl(a1, k, 64) * w;
  }
  t0 = tanh_fast(t0); t1 = tanh_fast(t1);
  float w2 = sem_w2[lane];
  float w0 = t0*w2, w1 = t1*w2;
  #pragma unroll
  for (int s = 1; s < 64; s <<= 1){
    w0 += __shfl_xor(w0, s, 64);
    w1 += __shfl_xor(w1, s, 64);
  }
  float mx = fmaxf(w0, w1);
  float e0 = __expf(w0 - mx), e1 = __expf(w1 - mx);
  float denom = e0 + e1 + 1e-10f;
  float b0 = e0/denom, b1 = e1/denom;
  float emb = b0*a0 + b1*a1;
  float pl = emb * pred_w[lane];
  #pragma unroll
  for (int s = 1; s < 64; s <<= 1) pl += __shfl_xor(pl, s, 64);
  if (lane == 0) out[n] = sigm(pl + pred_b[0]);
}

extern "C" void kernel_launch(void* const* d_in, const int* in_sizes, int n_in,
                              void* d_out, int out_size, void* d_ws, size_t ws_size,
                              hipStream_t stream)
{
  (void)in_sizes; (void)n_in; (void)out_size; (void)ws_size;
  const float* x         = (const float*)d_in[0];
  const int*   adj       = (const int*)d_in[1];
  const float* W_ih      = (const float*)d_in[2];
  const float* W_hh      = (const float*)d_in[3];
  const float* b_ih      = (const float*)d_in[4];
  const float* b_hh      = (const float*)d_in[5];
  const float* gat_w     = (const float*)d_in[6];
  const float* gat_wu    = (const float*)d_in[7];
  const float* gat_wv    = (const float*)d_in[8];
  const float* gat_bias  = (const float*)d_in[9];
  const float* proj_w    = (const float*)d_in[10];
  const float* proj_b    = (const float*)d_in[11];
  const float* mlp_self_w= (const float*)d_in[12];
  const float* mlp_self_b= (const float*)d_in[13];
  const float* mlp_pos_w = (const float*)d_in[14];
  const float* mlp_pos_b = (const float*)d_in[15];
  const float* sem_w1    = (const float*)d_in[16];
  const float* sem_b1    = (const float*)d_in[17];
  const float* sem_w2    = (const float*)d_in[18];
  const float* pred_w    = (const float*)d_in[19];
  const float* pred_b    = (const float*)d_in[20];
  float* out = (float*)d_out;
  float* ws  = (float*)d_ws;

  float* h     = ws + 0;         // 262144
  float* supt  = ws + 262144;    // 262144  [64][4096]
  float* f1t   = ws + 524288;    // 32768   [8][4096]
  float* f2    = ws + 557056;    // 32768   [4096][8]
  float* posg  = ws + 589824;    // 262144
  float* s0    = ws + 851968;    // 262144
  float* s1    = ws + 1114112;   // 262144
  // adjm overlays s0+s1 (2MB): written by k2c, consumed by k3, dead before k4 writes s0/s1
  unsigned long long* adjm = (unsigned long long*)(ws + 851968);
  float* part  = ws + 1376256;   // 1024*130
  float* bmax  = ws + 1509376;   // 1024*8
  float* maxf1 = ws + 1517568;   // 8
  float* stats = ws + 1517576;   // 129
  float* wtproj= ws + 1517712;   // 4096
  float* wtself= wtproj + 4096;
  float* wtpos = wtself + 4096;
  float* wtsem = wtpos  + 4096;

  k0_prep<<<16, 256, 0, stream>>>(proj_w, mlp_self_w, mlp_pos_w, sem_w1,
                                  wtproj, wtself, wtpos, wtsem);
  k1_gru<<<256, 256, 0, stream>>>(x, W_ih, W_hh, b_ih, b_hh, h);
  k2_sup<<<1024, 256, 0, stream>>>(h, gat_w, gat_wu, gat_wv, supt, f1t, f2, bmax);
  k2b_max<<<1, 256, 0, stream>>>(bmax, maxf1);
  k2c_pack<<<1024, 256, 0, stream>>>(adj, adjm);
  k3_gat<<<1024, 256, 0, stream>>>(adjm, supt, f1t, f2, maxf1, posg);
  k4_mix<<<1024, 256, 0, stream>>>(h, posg, gat_bias, proj_b, wtproj, wtself, wtpos,
                                   mlp_self_b, mlp_pos_b, s0, s1, part);
  k5_stats<<<1, 1024, 0, stream>>>(part, stats);
  k6_sem<<<1024, 256, 0, stream>>>(s0, s1, stats, wtsem, sem_b1, sem_w2, pred_w, pred_b, out);
}